// Round 7
// baseline (84.459 us; speedup 1.0000x reference)
//
#include <hip/hip_runtime.h>

#define NB     32
#define NATOM  48
#define NGRID  128
#define KT     16                         /* grid points per block (2 sub-tiles) */
#define NTHR   384                        /* 6 waves: thread = (n, kq 0..7) */

#define MBTR_ELEMS (NB*16*NGRID)          /* 65536 */
#define DIV_PER_B  (16*NGRID*NATOM*3)     /* 294912 */
#define PANE       (NGRID*NATOM*3)        /* 18432 floats per (e1,e2) pane */
#define MSTRIDE    49                     /* padded n-stride for M table */

// Fused MBTR fwd+div, register-direct output, SUB-TILE PIPELINED.
// R6 lesson: halving phase-1 issue and cutting store instrs 3x was exactly
// neutral -> neither is binding. Remaining structural cost: the div-store
// drain is a serial tail (all stores issued at kernel end; 1 block/CU means
// nothing overlaps it). This version splits the 16-k tile into two 8-k
// passes: pass-0 stores are issued BEFORE pass-1 compute, so they retire
// under ~3-4us of compute; barrier#2's implicit vmcnt(0) is then cheap and
// only pass-1's stores remain as an unhidden tail.
// Mrec slabs are disjoint per pass (kk 0..7 vs 8..15) -> no WAR across
// barriers. Species-segmented static-e loop kept verbatim (R4 lesson).
__device__ __forceinline__ void accum_pass(
        const float4* __restrict__ pos, const int* __restrict__ order,
        const int so[5], const float4 rn, const int n, const float gk,
        const float mlc, float (&A)[4][3], float (&M)[4])
{
    const float isc = 16.986436005760382f;          // 20*sqrt(log2e/2)
    const float tBc = 23.548200452219559f;          // 20/sqrt(log2e/2)
    const float l2e = 1.4426950408889634f;
    #pragma unroll
    for (int e = 0; e < 4; ++e) {           // e STATIC -> A[e] in registers
        for (int i = so[e]; i < so[e + 1]; ++i) {
            const int    m  = order[i];     // uniform -> broadcast
            const float4 rm = pos[m];       // uniform -> broadcast
            const float ddx = rn.x - rm.x, ddy = rn.y - rm.y, ddz = rn.z - rm.z;
            float d2 = ddx*ddx + ddy*ddy + ddz*ddz;
            const bool self = (m == n);
            d2 = self ? 1.0f : d2;                        // rsq NaN guard
            const float gf  = __builtin_amdgcn_rsqf(d2);  // 1/d
            const float c1  = gf * isc;
            const float d   = d2 * gf;
            float base = fmaf(d, l2e, mlc);               // wf & coef folded
            base = self ? 1e30f : base;                   // kill self pair
            const float bq  = (gf * gf) * tBc;
            const float tt  = gk - c1;
            const float ex  = exp2f(-fmaf(tt, tt, base)); // coef*wf*gv
            M[e] += ex;
            const float p   = ex * fmaf(tt, bq, 1.0f);
            A[e][0] = fmaf(-p, gf * ddx, A[e][0]);
            A[e][1] = fmaf(-p, gf * ddy, A[e][1]);
            A[e][2] = fmaf(-p, gf * ddz, A[e][2]);
        }
    }
}

__global__ __launch_bounds__(NTHR)
void mbtr_fused(const float* __restrict__ r, const int* __restrict__ z,
                const float* __restrict__ grid, float* __restrict__ out)
{
    const int kt = blockIdx.x, b = blockIdx.y, t = threadIdx.x;
    const int k0 = kt * KT;

    __shared__ float4 pos[NATOM];
    __shared__ int    zl[NATOM];
    __shared__ int    order[NATOM];
    __shared__ int    soff_s[5];
    __shared__ float  Mrec[KT * 4 * MSTRIDE];   /* [kk][e][49], kk 0..15 */

    // ---- setup: wave 0 loads atoms, builds species-sorted order ----
    if (t < 64) {
        const bool isatom = (t < NATOM);
        int myz = 999;
        if (isatom) {
            myz = z[t];
            zl[t] = myz;
            const float* rp = r + ((size_t)b * NATOM + t) * 3;
            pos[t] = make_float4(rp[0], rp[1], rp[2], 0.f);
        }
        const unsigned long long m0 = __ballot(myz == 0);
        const unsigned long long m1 = __ballot(myz == 1);
        const unsigned long long m2 = __ballot(myz == 2);
        const unsigned long long m3 = __ballot(myz == 3);
        const int c0 = __popcll(m0), c1 = __popcll(m1), c2 = __popcll(m2);
        if (isatom) {
            const unsigned long long mm = (myz == 0) ? m0 : (myz == 1) ? m1
                                        : (myz == 2) ? m2 : m3;
            const int base = (myz == 0) ? 0 : (myz == 1) ? c0
                           : (myz == 2) ? c0 + c1 : c0 + c1 + c2;
            const int rank = __popcll(mm & ((1ull << t) - 1ull));
            order[base + rank] = t;
        }
        if (t == 0) {
            soff_s[0] = 0; soff_s[1] = c0; soff_s[2] = c0 + c1;
            soff_s[3] = c0 + c1 + c2; soff_s[4] = NATOM;
        }
    }
    __syncthreads();

    const int n  = t % NATOM;
    const int kq = t / NATOM;               // 0..7
    const float dx   = grid[1] - grid[0];
    const float coef = dx * 7.9788456080286535f;     // dx*20/sqrt(2pi)
    const float mlc  = -__log2f(coef);
    const float isc  = 16.986436005760382f;
    const float4 rn = pos[n];
    const int   zn  = zl[n];
    int so[5];
    #pragma unroll
    for (int e = 0; e < 5; ++e) so[e] = soff_s[e];

    float* divout = out + MBTR_ELEMS + (size_t)b * DIV_PER_B;

    #pragma unroll
    for (int h = 0; h < 2; ++h) {
        const int k = k0 + 8 * h + kq;
        const float gk = grid[k] * isc;

        float A[4][3] = {{0.f}};
        float M[4]    = {0.f};
        accum_pass(pos, order, so, rn, n, gk, mlc, A, M);

        {   // M table -> disjoint slab per pass (no WAR across barriers)
            float* mr = Mrec + (kq + 8 * h) * (4 * MSTRIDE) + n;
            #pragma unroll
            for (int e = 0; e < 4; ++e) mr[e * MSTRIDE] = M[e];
        }
        // Pass 0: no global stores in flight yet -> barrier drain is LDS-only.
        // Pass 1: pass-0 div stores have had the whole pass-1 compute to
        // retire -> vmcnt drain cheap.
        __syncthreads();

        if (t < 128) {   // mbtr rows for this sub-tile: (pane, kk 0..7)
            const int mpane = t >> 3, mkk = (t & 7) + 8 * h;
            const int me1 = mpane >> 2, me2 = mpane & 3;
            const float* tr2 = Mrec + mkk * (4 * MSTRIDE) + me2 * MSTRIDE;
            float s = 0.f;
            #pragma unroll
            for (int nn = 0; nn < NATOM; ++nn)
                s += (zl[nn] == me1) ? tr2[nn] : 0.f;
            out[(size_t)b * 2048 + mpane * NGRID + k0 + mkk] = s;
        }

        // div stores for this sub-tile, straight from registers
        float* basep = divout + (size_t)k * 144 + n * 3;
        #pragma unroll
        for (int e1 = 0; e1 < 4; ++e1) {
            const bool s1 = (zn == e1);
            #pragma unroll
            for (int e2 = 0; e2 < 4; ++e2) {
                const bool s2 = (zn == e2);
                float3 v;
                v.x = (s1 ? A[e2][0] : 0.f) + (s2 ? A[e1][0] : 0.f);
                v.y = (s1 ? A[e2][1] : 0.f) + (s2 ? A[e1][1] : 0.f);
                v.z = (s1 ? A[e2][2] : 0.f) + (s2 ? A[e1][2] : 0.f);
                *(float3*)(basep + (e1 * 4 + e2) * PANE) = v;
            }
        }
    }
}

extern "C" void kernel_launch(void* const* d_in, const int* in_sizes, int n_in,
                              void* d_out, int out_size, void* d_ws, size_t ws_size,
                              hipStream_t stream)
{
    const float* r    = (const float*)d_in[0];
    const int*   z    = (const int*)  d_in[1];
    const float* grid = (const float*)d_in[2];
    float* out = (float*)d_out;
    (void)d_ws; (void)ws_size;

    mbtr_fused<<<dim3(NGRID / KT, NB), NTHR, 0, stream>>>(r, z, grid, out);
}

// Round 8
// 79.614 us; speedup vs baseline: 1.0609x; 1.0609x over previous
//
#include <hip/hip_runtime.h>

#define NB     32
#define NATOM  48
#define NGRID  128
#define KT     8                          /* grid points per block */
#define NTHR   384                        /* 6 waves: thread = (n, kk) */

#define MBTR_ELEMS (NB*16*NGRID)          /* 65536 */
#define DIV_PER_B  (16*NGRID*NATOM*3)     /* 294912 */
#define PANE       (NGRID*NATOM*3)        /* 18432 floats per (e1,e2) pane */
#define MSTRIDE    49                     /* padded n-stride for M table */

// Fused MBTR fwd+div, register-direct output, SORTED-POSITION inner loop.
// R5/R6/R7 A-B established the kernel is LATENCY-bound: the old inner loop's
// order[i] -> pos[order[i]] dependent LDS chain (~240 cyc/iter, un-unrollable
// behind dynamic segment bounds) serialized phase 1. Fix: atoms are written
// SPECIES-SORTED into pos_s at setup (pos_s[i] = {x,y,z, atom_id}), so the
// inner loop reads a static loop-counter address -- no indirection, and
// unroll-4 lets independent ds_read_b128s pipeline. Static-e segmented
// accumulation kept (R4 lesson: runtime-e forces cndmask/scratch).
// Self-pair detected via rm.w == (float)n. Structure otherwise identical to
// R5 (best known: KT=8, 512 blocks, 384 thr, register-direct div stores).
__global__ __launch_bounds__(NTHR)
void mbtr_fused(const float* __restrict__ r, const int* __restrict__ z,
                const float* __restrict__ grid, float* __restrict__ out)
{
    const int kt = blockIdx.x, b = blockIdx.y, t = threadIdx.x;
    const int k0 = kt * KT;

    __shared__ float4 pos_s[NATOM + 1];   /* species-sorted; +1 prefetch pad */
    __shared__ int    zl[NATOM];
    __shared__ int    soff_s[5];
    __shared__ float  znpos[NATOM * 3];   /* unsorted positions for rn */
    __shared__ float  Mrec[KT * 4 * MSTRIDE];   /* [kk][e][49] */

    // ---- setup: wave 0 loads atoms, scatters them species-sorted ----
    if (t < 64) {
        const bool isatom = (t < NATOM);
        int myz = 999;
        float rx = 0.f, ry = 0.f, rz = 0.f;
        if (isatom) {
            myz = z[t];
            zl[t] = myz;
            const float* rp = r + ((size_t)b * NATOM + t) * 3;
            rx = rp[0]; ry = rp[1]; rz = rp[2];
            znpos[t * 3 + 0] = rx; znpos[t * 3 + 1] = ry; znpos[t * 3 + 2] = rz;
        }
        const unsigned long long m0 = __ballot(myz == 0);
        const unsigned long long m1 = __ballot(myz == 1);
        const unsigned long long m2 = __ballot(myz == 2);
        const unsigned long long m3 = __ballot(myz == 3);
        const int c0 = __popcll(m0), c1 = __popcll(m1), c2 = __popcll(m2);
        if (isatom) {
            const unsigned long long mm = (myz == 0) ? m0 : (myz == 1) ? m1
                                        : (myz == 2) ? m2 : m3;
            const int base = (myz == 0) ? 0 : (myz == 1) ? c0
                           : (myz == 2) ? c0 + c1 : c0 + c1 + c2;
            const int rank = __popcll(mm & ((1ull << t) - 1ull));
            pos_s[base + rank] = make_float4(rx, ry, rz, (float)t);
        }
        if (t == 0) {
            soff_s[0] = 0; soff_s[1] = c0; soff_s[2] = c0 + c1;
            soff_s[3] = c0 + c1 + c2; soff_s[4] = NATOM;
            pos_s[NATOM] = make_float4(0.f, 0.f, 0.f, -1.f);  // prefetch pad
        }
    }
    __syncthreads();

    // ---- phase 1: thread = (n, kk), one grid point ----
    const int n  = t % NATOM;
    const int kk = t / NATOM;               // 0..7
    const float dx   = grid[1] - grid[0];
    const float coef = dx * 7.9788456080286535f;     // dx*20/sqrt(2pi)
    const float mlc  = -__log2f(coef);
    const float isc  = 16.986436005760382f;          // 20*sqrt(log2e/2)
    const float tBc  = 23.548200452219559f;          // 20/sqrt(log2e/2)
    const float l2e  = 1.4426950408889634f;
    const float gk   = grid[k0 + kk] * isc;
    const float nf   = (float)n;

    float A[4][3] = {{0.f}};
    float M[4]    = {0.f};
    const float rnx = znpos[n * 3 + 0];
    const float rny = znpos[n * 3 + 1];
    const float rnz = znpos[n * 3 + 2];
    const int   zn  = zl[n];
    int so[5];
    #pragma unroll
    for (int e = 0; e < 5; ++e) so[e] = soff_s[e];

    #pragma unroll
    for (int e = 0; e < 4; ++e) {           // e STATIC -> A[e] in registers
        #pragma unroll 4                    // static addr -> reads pipeline
        for (int i = so[e]; i < so[e + 1]; ++i) {
            const float4 rm = pos_s[i];     // static-address broadcast read
            const float ddx = rnx - rm.x, ddy = rny - rm.y, ddz = rnz - rm.z;
            float d2 = ddx*ddx + ddy*ddy + ddz*ddz;
            const bool self = (rm.w == nf);
            d2 = self ? 1.0f : d2;                        // rsq NaN guard
            const float gf  = __builtin_amdgcn_rsqf(d2);  // 1/d
            const float c1  = gf * isc;
            const float d   = d2 * gf;
            float base = fmaf(d, l2e, mlc);               // wf & coef folded
            base = self ? 1e30f : base;                   // kill self pair
            const float bq  = (gf * gf) * tBc;
            const float tt  = gk - c1;
            const float ex  = exp2f(-fmaf(tt, tt, base)); // coef*wf*gv
            M[e] += ex;
            const float p   = ex * fmaf(tt, bq, 1.0f);
            A[e][0] = fmaf(-p, gf * ddx, A[e][0]);
            A[e][1] = fmaf(-p, gf * ddy, A[e][1]);
            A[e][2] = fmaf(-p, gf * ddz, A[e][2]);
        }
    }

    {   // M table to LDS
        float* mr = Mrec + kk * (4 * MSTRIDE) + n;
        #pragma unroll
        for (int e = 0; e < 4; ++e) mr[e * MSTRIDE] = M[e];
    }

    // ---- phase 2a: div writes straight from registers ----
    // pane (e1,e2) value at (n,c) = (zn==e1)*A[e2][c] + (zn==e2)*A[e1][c]
    float* basep = out + MBTR_ELEMS + (size_t)b * DIV_PER_B
                 + (size_t)(k0 + kk) * 144 + n * 3;
    #pragma unroll
    for (int e1 = 0; e1 < 4; ++e1) {
        const bool s1 = (zn == e1);
        #pragma unroll
        for (int e2 = 0; e2 < 4; ++e2) {
            const bool s2 = (zn == e2);
            float3 v;
            v.x = (s1 ? A[e2][0] : 0.f) + (s2 ? A[e1][0] : 0.f);
            v.y = (s1 ? A[e2][1] : 0.f) + (s2 ? A[e1][1] : 0.f);
            v.z = (s1 ? A[e2][2] : 0.f) + (s2 ? A[e1][2] : 0.f);
            *(float3*)(basep + (e1 * 4 + e2) * PANE) = v;
        }
    }

    __syncthreads();

    // ---- phase 2b: mbtr reduction (threads 0..127: one (pane,kk) each) ----
    if (t < 128) {
        const int mpane = t >> 3, mkk = t & 7;
        const int me1 = mpane >> 2, me2 = mpane & 3;
        const float* tr2 = Mrec + mkk * (4 * MSTRIDE) + me2 * MSTRIDE;
        float s = 0.f;
        #pragma unroll
        for (int nn = 0; nn < NATOM; ++nn)
            s += (zl[nn] == me1) ? tr2[nn] : 0.f;
        out[(size_t)b * 2048 + mpane * NGRID + k0 + mkk] = s;
    }
}

extern "C" void kernel_launch(void* const* d_in, const int* in_sizes, int n_in,
                              void* d_out, int out_size, void* d_ws, size_t ws_size,
                              hipStream_t stream)
{
    const float* r    = (const float*)d_in[0];
    const int*   z    = (const int*)  d_in[1];
    const float* grid = (const float*)d_in[2];
    float* out = (float*)d_out;
    (void)d_ws; (void)ws_size;

    mbtr_fused<<<dim3(NGRID / KT, NB), NTHR, 0, stream>>>(r, z, grid, out);
}